// Round 7
// baseline (128.516 us; speedup 1.0000x reference)
//
#include <hip/hip_runtime.h>
#include <hip/hip_fp16.h>
#include <math.h>

typedef _Float16 f16;
typedef _Float16 half8 __attribute__((ext_vector_type(8)));
typedef _Float16 half4v __attribute__((ext_vector_type(4)));
typedef _Float16 half2v __attribute__((ext_vector_type(2)));
typedef float f32x4 __attribute__((ext_vector_type(4)));

// ---------------- ws layout (bytes) ----------------
// region A [0, 44,564,480): fmapT fp16 [87040][256]   (levels: 0,65536,81920,86016 px)
//   aliased AFTER roi_align has consumed fmapT (stream-sequential):
//     sh1  @ 0MB  fp16 [1024][1024]
//     sh2  @ 2MB  fp16 [1024][1024]
//     lraw @ 4MB  fp32 [1024][512]
//     w2t  @ 6MB  fp16 [1024][1024]
//     wcat @ 8MB  fp16 [512][1024]
//     bcat @ 9MB  fp32 [512]
//     part @10MB  fp32 [8][1024][1024] max = 32MB (ends 42MB < 44.56MB)
// pooled @ 44,564,480  fp16 [1024][49*256]
// w1t    @ 70,254,592  fp16 [1024][49*256]    (total 95,944,704 B)

__device__ __forceinline__ void gload16(const f16* g, f16* lds) {
  __builtin_amdgcn_global_load_lds(
      (const __attribute__((address_space(1))) unsigned int*)g,
      (__attribute__((address_space(3))) unsigned int*)lds, 16, 0, 0);
}

// ---- merged fmap transpose v3: fp32 [256][Ppix] -> fp16 [Ppix][256], 128 px/block ----
// 512B-contiguous reads per channel (4x longer DRAM streams than v2).
// 64KB LDS [128][256] f16, XOR-swizzled: addr(px,c) = px*256 + (c ^ (((px>>2)&31)<<3)).
__global__ __launch_bounds__(256) void fmap_all_k(const float* __restrict__ p2,
                                                  const float* __restrict__ p3,
                                                  const float* __restrict__ p4,
                                                  const float* __restrict__ p5,
                                                  f16* __restrict__ dst) {
  const int b = blockIdx.x;
  const float* src;
  int Ppix, p0;
  size_t dstoff;
  if (b < 512)      { src = p2; Ppix = 65536; dstoff = 0;     p0 = b * 128; }
  else if (b < 640) { src = p3; Ppix = 16384; dstoff = 65536; p0 = (b - 512) * 128; }
  else if (b < 672) { src = p4; Ppix = 4096;  dstoff = 81920; p0 = (b - 640) * 128; }
  else              { src = p5; Ppix = 1024;  dstoff = 86016; p0 = (b - 672) * 128; }
  __shared__ __align__(16) f16 tile[128 * 256];  // 64 KB, swizzled
  const int t = threadIdx.x;
  // phase 1: wave = 2 channel-pairs; 32 lanes x float4 = 128 px per channel.
  const int px4 = (t & 31) * 4;   // 0..124
  const int cp = (t >> 5) * 2;    // 0,2,..,14
#pragma unroll 4
  for (int i = 0; i < 16; i++) {
    const int c = i * 16 + cp;
    const float4 va = *(const float4*)&src[(size_t)c * Ppix + p0 + px4];
    const float4 vb = *(const float4*)&src[(size_t)(c + 1) * Ppix + p0 + px4];
    const float a_[4] = {va.x, va.y, va.z, va.w};
    const float b_[4] = {vb.x, vb.y, vb.z, vb.w};
#pragma unroll
    for (int j = 0; j < 4; j++) {
      const int px = px4 + j;
      const int cs = c ^ (((px >> 2) & 31) << 3);  // XOR bits 3..7, parity kept
      half2v h = {(f16)a_[j], (f16)b_[j]};
      *(half2v*)&tile[px * 256 + cs] = h;
    }
  }
  __syncthreads();
  // phase 2: per wave-instruction: 2 px rows x 512B contiguous stores
  f16* d = dst + (dstoff + (size_t)p0) * 256;
  const int c8 = (t & 31) * 8;
#pragma unroll 4
  for (int i = 0; i < 16; i++) {
    const int px = (t >> 5) * 16 + i;
    const int c8s = c8 ^ (((px >> 2) & 31) << 3);  // same-8-group shift, 16B aligned
    const half8 o = *(const half8*)&tile[px * 256 + c8s];
    *(half8*)&d[px * 256 + c8] = o;
  }
}

// ---- w1 (r3-proven): fp32 [k][c*49+pq] -> fp16 [k][pq*256+c] ----
__global__ __launch_bounds__(256) void w1_t_k(const float* __restrict__ w1,
                                              f16* __restrict__ w1t) {
  __shared__ __align__(16) f16 tile[49 * 260];
  const int k = blockIdx.x, t = threadIdx.x;
  const float* src = w1 + (size_t)k * 12544;
  f16* dst = w1t + (size_t)k * 12544;
#pragma unroll 7
  for (int i = 0; i < 49; i++) {
    const int idx = i * 256 + t;  // = c*49 + pq
    const int c = idx / 49, pq = idx % 49;
    tile[pq * 260 + c] = (f16)src[idx];
  }
  __syncthreads();
#pragma unroll
  for (int i = 0; i < 7; i++) {
    const int h8 = i * 256 + t;
    if (h8 < 1568) {
      const int pq = h8 >> 5, c8 = (h8 & 31) * 8;
      const half4v lo = *(const half4v*)&tile[pq * 260 + c8];
      const half4v hi = *(const half4v*)&tile[pq * 260 + c8 + 4];
      half8 o;
      o[0] = lo[0]; o[1] = lo[1]; o[2] = lo[2]; o[3] = lo[3];
      o[4] = hi[0]; o[5] = hi[1]; o[6] = hi[2]; o[7] = hi[3];
      *(half8*)&dst[pq * 256 + c8] = o;
    }
  }
}

// ---- merged small converts (r3-proven) ----
__global__ void prep_small_k(const float* __restrict__ conv2_w,
                             const float* __restrict__ lw, const float* __restrict__ lb,
                             const float* __restrict__ bw, const float* __restrict__ bb,
                             f16* __restrict__ w2t, f16* __restrict__ wcat,
                             float* __restrict__ bcat) {
  const int i = blockIdx.x * 256 + threadIdx.x;
  if (i < 262144) {
    const float4 v = ((const float4*)conv2_w)[i];
    half4v o = {(f16)v.x, (f16)v.y, (f16)v.z, (f16)v.w};
    ((half4v*)w2t)[i] = o;
  } else if (i < 262144 + 131072) {
    const int idx4 = i - 262144;
    const int elem = idx4 * 4;
    const int row = elem >> 10, col = elem & 1023;
    half4v o;
#pragma unroll
    for (int j = 0; j < 4; j++) {
      float v = 0.f;
      if (row < 81) v = lw[row * 1024 + col + j];
      else if (row < 405) v = bw[(row - 81) * 1024 + col + j];
      o[j] = (f16)v;
    }
    ((half4v*)wcat)[idx4] = o;
  } else if (i < 262144 + 131072 + 128) {
    const int j = (i - 393216) * 4;
    float r[4];
#pragma unroll
    for (int q = 0; q < 4; q++) {
      const int c = j + q;
      float bv = 0.f;
      if (c < 81) bv = lb[c];
      else if (c < 405) bv = bb[c - 81];
      r[q] = bv;
    }
    float4 o;
    o.x = r[0]; o.y = r[1]; o.z = r[2]; o.w = r[3];
    *(float4*)&bcat[j] = o;
  }
}

// ---- roi align (r3-proven): 2 rois/block, half2 loads; rows>=1000 zeroed ----
__global__ __launch_bounds__(256) void roi_align_k(const float* __restrict__ rois,
                                                   const f16* __restrict__ fmapT,
                                                   f16* __restrict__ pooled) {
  const int t = threadIdx.x;
  const int hf = t >> 7, tp = t & 127;
  const int r = blockIdx.x * 2 + hf;
  __shared__ int s_lo[2][14], s_hi[2][14], s_val[2][14];
  __shared__ float s_w[2][14];
  const bool live = (r < 1000);
  int H = 2, off = 0;
  if (live) {
    const float x1 = rois[r * 4 + 0], y1 = rois[r * 4 + 1];
    const float x2 = rois[r * 4 + 2], y2 = rois[r * 4 + 3];
    const float s = sqrtf(fmaxf((y2 - y1) * (x2 - x1), 0.f));
    const float lf = logf(s / 224.0f) / 0.69314718055994531f;
    int lv = (int)rintf(lf) + 4;
    lv = lv < 2 ? 2 : (lv > 5 ? 5 : lv);
    const int li = lv - 2;
    H = 256 >> li;
    off = (li == 0) ? 0 : (li == 1) ? 65536 : (li == 2) ? 81920 : 86016;
    const float Hm1 = (float)(H - 1);
    if (tp < 14) {
      const bool isx = tp >= 7;
      const int i = isx ? tp - 7 : tp;
      const float b1 = (isx ? x1 : y1) * (1.0f / 1024.0f);
      const float b2 = (isx ? x2 : y2) * (1.0f / 1024.0f);
      const float g = (float)i / 6.0f;
      const float coord = b1 * Hm1 + g * ((b2 - b1) * Hm1);
      const int valid = (coord >= 0.f) && (coord <= Hm1);
      float c = fminf(fmaxf(coord, 0.f), Hm1);
      float lo = floorf(c);
      s_lo[hf][tp] = (int)lo;
      s_hi[hf][tp] = (int)fminf(lo + 1.f, Hm1);
      s_w[hf][tp] = c - lo;
      s_val[hf][tp] = valid;
    }
  }
  __syncthreads();
  f16* outp = pooled + (size_t)r * 12544 + 2 * tp;
  if (!live) {
#pragma unroll 7
    for (int i = 0; i < 49; i++) {
      half2v z = {(f16)0.f, (f16)0.f};
      *(half2v*)&outp[i * 256] = z;
    }
    return;
  }
  const f16* base = fmapT + (size_t)off * 256 + 2 * tp;
  for (int py = 0; py < 7; py++) {
    const int ylo = s_lo[hf][py], yhi = s_hi[hf][py], vy = s_val[hf][py];
    const float wy = s_w[hf][py];
    for (int px = 0; px < 7; px++) {
      const int xlo = s_lo[hf][7 + px], xhi = s_hi[hf][7 + px], vx = s_val[hf][7 + px];
      const float wx = s_w[hf][7 + px];
      const half2v v00 = *(const half2v*)&base[(size_t)(ylo * H + xlo) * 256];
      const half2v v01 = *(const half2v*)&base[(size_t)(ylo * H + xhi) * 256];
      const half2v v10 = *(const half2v*)&base[(size_t)(yhi * H + xlo) * 256];
      const half2v v11 = *(const half2v*)&base[(size_t)(yhi * H + xhi) * 256];
      half2v o;
#pragma unroll
      for (int q = 0; q < 2; q++) {
        const float top = (float)v00[q] * (1.f - wx) + (float)v01[q] * wx;
        const float bot = (float)v10[q] * (1.f - wx) + (float)v11[q] * wx;
        float vv = top * (1.f - wy) + bot * wy;
        if (!(vy && vx)) vv = 0.f;
        o[q] = (f16)vv;
      }
      *(half2v*)&outp[(py * 7 + px) * 256] = o;
    }
  }
}

// ---- GEMM1 engine v2 (r5-proven): 8-wave 256x128, BK=32, 4-slot ring ----
__global__ __launch_bounds__(512) void gemm1_d2(
    const f16* __restrict__ A, const f16* __restrict__ B, float* __restrict__ part,
    int K, int kPerSplit) {
  __shared__ __align__(16) f16 As[4][256 * 32];   // 64 KB
  __shared__ __align__(16) f16 Bs[4][128 * 32];   // 32 KB
  const int t = threadIdx.x;

  int lid = blockIdx.x + 8 * (blockIdx.y + 4 * blockIdx.z);
  const int chunk = (8 * 4 * (int)gridDim.z) >> 3;
  lid = (lid & 7) * chunk + (lid >> 3);
  const int bx = lid & 7;
  const int by = (lid >> 3) & 3;
  const int bz = lid >> 5;

  const int m0 = by * 256, n0 = bx * 128;
  const int wid = t >> 6, lane = t & 63;
  const int wr = (wid & 3) * 64;   // 4 M-waves
  const int wc = (wid >> 2) * 64;  // 2 N-waves
  const int lrow = lane & 15;
  const int lsl = lane >> 4;
  const int srow = t >> 2;                              // 0..127 staging row
  const int scol = (((t & 3) ^ ((t >> 3) & 3)) << 3);   // pre-swizzled source slot
  const int kz0 = bz * kPerSplit;
  const int nIter = kPerSplit >> 5;

  f32x4 acc[4][4] = {};
  const f16* Ab = A + (size_t)(m0 + srow) * K + kz0 + scol;
  const f16* Bb = B + (size_t)(n0 + srow) * K + kz0 + scol;
  f16* asb = &As[0][0] + wid * 512;  // wave-uniform base within slot
  f16* bsb = &Bs[0][0] + wid * 512;

  // one stage group per K-tile: 3 gload_lds, emission order pinned
#define STG(kt) do {                                                           \
    const int sl_ = (kt) & 3; const size_t ko_ = (size_t)(kt) * 32;            \
    gload16(Ab + ko_, asb + sl_ * 8192);                                       \
    gload16(Ab + (size_t)128 * K + ko_, asb + sl_ * 8192 + 4096);              \
    gload16(Bb + ko_, bsb + sl_ * 4096);                                       \
    __builtin_amdgcn_sched_barrier(0);                                         \
  } while (0)

  STG(0);
  STG(1);
  asm volatile("s_waitcnt vmcnt(3)" ::: "memory");  // tile 0 resident
  __builtin_amdgcn_sched_barrier(0);
  __builtin_amdgcn_s_barrier();

  for (int kt = 0; kt < nIter; ++kt) {
    const int sl = kt & 3;
    const f16* as = &As[sl][0];
    const f16* bs = &Bs[sl][0];
    half8 aF[4], bF[4];
#pragma unroll
    for (int m = 0; m < 4; m++) {
      const int r_ = wr + m * 16 + lrow;
      aF[m] = *(const half8*)&as[r_ * 32 + ((lsl ^ ((r_ >> 1) & 3)) << 3)];
    }
#pragma unroll
    for (int n = 0; n < 4; n++) {
      const int r_ = wc + n * 16 + lrow;
      bF[n] = *(const half8*)&bs[r_ * 32 + ((lsl ^ ((r_ >> 1) & 3)) << 3)];
    }
    if (kt + 2 < nIter) STG(kt + 2);
    __builtin_amdgcn_s_setprio(1);
#pragma unroll
    for (int m = 0; m < 4; m++)
#pragma unroll
      for (int n = 0; n < 4; n++)
        acc[m][n] = __builtin_amdgcn_mfma_f32_16x16x32_f16(aF[m], bF[n], acc[m][n], 0, 0, 0);
    __builtin_amdgcn_s_setprio(0);
    // drain tile kt+1's 3 loads (kt+2's stay in flight); all waves sync
    if (kt + 2 < nIter) { asm volatile("s_waitcnt vmcnt(3)" ::: "memory"); }
    else                { asm volatile("s_waitcnt vmcnt(0)" ::: "memory"); }
    __builtin_amdgcn_sched_barrier(0);
    __builtin_amdgcn_s_barrier();
  }
#undef STG

  float* outp = part + (size_t)bz * (1024 * 1024);
#pragma unroll
  for (int m = 0; m < 4; m++) {
    const int rr = m0 + wr + m * 16 + lsl * 4;
#pragma unroll
    for (int n = 0; n < 4; n++) {
      const int cc = n0 + wc + n * 16 + lrow;
#pragma unroll
      for (int j = 0; j < 4; j++)
        outp[(size_t)(rr + j) * 1024 + cc] = acc[m][n][j];
    }
  }
}

// ---- GEMM2/3 engine (r3-proven): 3-buffer pipeline, fp32 partials ----
__global__ __launch_bounds__(256) void gemm_nt_p3(
    const f16* __restrict__ A, const f16* __restrict__ B, float* __restrict__ part,
    int K, int kPerSplit, int ldc) {
  __shared__ __align__(16) f16 As[3][128 * 32];
  __shared__ __align__(16) f16 Bs[3][128 * 32];
  const int t = threadIdx.x;

  const int gx = gridDim.x, gy = gridDim.y;
  int lid = blockIdx.x + gx * (blockIdx.y + gy * blockIdx.z);
  const int chunk = (gx * gy * (int)gridDim.z) >> 3;
  lid = (lid & 7) * chunk + (lid >> 3);
  const int bx = lid % gx;
  const int tmp = lid / gx;
  const int by = tmp % gy;
  const int bz = tmp / gy;

  const int m0 = by * 128;
  const int n0 = bx * 128;
  const int wid = t >> 6;
  const int lane = t & 63;
  const int wr = (wid >> 1) * 64;
  const int wc = (wid & 1) * 64;
  const int lrow = lane & 15;
  const int lsl = lane >> 4;
  const int rowA = t >> 2;
  const int c8 = (((t & 3) ^ ((rowA >> 1) & 3)) << 3);
  const int kz0 = bz * kPerSplit;
  const int nIter = kPerSplit >> 5;

  f32x4 acc[4][4] = {};
  const f16* Ab = A + (size_t)m0 * K + kz0 + c8;
  const f16* Bb = B + (size_t)n0 * K + kz0 + c8;

#define STAGE(buf, it)                                                        \
  do {                                                                        \
    const int ko = (it) * 32;                                                 \
    gload16(Ab + (size_t)rowA * K + ko, &As[buf][wid * 512]);                 \
    gload16(Ab + (size_t)(rowA + 64) * K + ko, &As[buf][2048 + wid * 512]);   \
    gload16(Bb + (size_t)rowA * K + ko, &Bs[buf][wid * 512]);                 \
    gload16(Bb + (size_t)(rowA + 64) * K + ko, &Bs[buf][2048 + wid * 512]);   \
  } while (0)

#define COMPUTE(buf)                                                          \
  do {                                                                        \
    half8 aF[4], bF[4];                                                       \
    _Pragma("unroll") for (int m = 0; m < 4; m++) {                           \
      const int rr_ = wr + m * 16 + lrow;                                     \
      aF[m] = *(const half8*)&As[buf][rr_ * 32 + ((lsl ^ ((rr_ >> 1) & 3)) << 3)]; \
    }                                                                         \
    _Pragma("unroll") for (int n = 0; n < 4; n++) {                           \
      const int rr_ = wc + n * 16 + lrow;                                     \
      bF[n] = *(const half8*)&Bs[buf][rr_ * 32 + ((lsl ^ ((rr_ >> 1) & 3)) << 3)]; \
    }                                                                         \
    __builtin_amdgcn_s_setprio(1);                                            \
    _Pragma("unroll") for (int m = 0; m < 4; m++)                             \
      _Pragma("unroll") for (int n = 0; n < 4; n++)                           \
        acc[m][n] = __builtin_amdgcn_mfma_f32_16x16x32_f16(aF[m], bF[n], acc[m][n], 0, 0, 0); \
    __builtin_amdgcn_s_setprio(0);                                            \
  } while (0)

  STAGE(0, 0);
  STAGE(1, 1);
  int bc = 0;
  for (int it = 0; it < nIter - 2; ++it) {
    const int bs_ = (bc == 0) ? 2 : bc - 1;
    STAGE(bs_, it + 2);
    asm volatile("s_waitcnt vmcnt(8)" ::: "memory");
    __builtin_amdgcn_sched_barrier(0);
    __builtin_amdgcn_s_barrier();
    COMPUTE(bc);
    __builtin_amdgcn_s_barrier();
    bc = (bc == 2) ? 0 : bc + 1;
  }
  asm volatile("s_waitcnt vmcnt(4)" ::: "memory");
  __builtin_amdgcn_sched_barrier(0);
  __builtin_amdgcn_s_barrier();
  COMPUTE(bc);
  __builtin_amdgcn_s_barrier();
  bc = (bc == 2) ? 0 : bc + 1;
  asm volatile("s_waitcnt vmcnt(0)" ::: "memory");
  __builtin_amdgcn_sched_barrier(0);
  __builtin_amdgcn_s_barrier();
  COMPUTE(bc);
#undef STAGE
#undef COMPUTE

  const size_t slice = (size_t)gy * 128 * ldc;
#pragma unroll
  for (int m = 0; m < 4; m++) {
#pragma unroll
    for (int n = 0; n < 4; n++) {
#pragma unroll
      for (int j = 0; j < 4; j++) {
        const int rr = m0 + wr + m * 16 + ((lane >> 4) << 2) + j;
        const int cc = n0 + wc + n * 16 + (lane & 15);
        part[(size_t)bz * slice + (size_t)rr * ldc + cc] = acc[m][n][j];
      }
    }
  }
}

// ---- split-K reduce + epilogue. MODE 1: bias+BN+ReLU->f16; MODE 2: +bias->f32 ----
template <int Z, int MODE>
__global__ void reduce_ep_k(const float* __restrict__ part, int sliceE, int ldc,
                            const float* __restrict__ bias, const float* __restrict__ g,
                            const float* __restrict__ b, const float* __restrict__ m,
                            const float* __restrict__ v, void* __restrict__ out) {
  const int i4 = (blockIdx.x * 256 + threadIdx.x) * 4;
  float4 s = *(const float4*)(part + i4);
#pragma unroll
  for (int z = 1; z < Z; z++) {
    const float4 p = *(const float4*)(part + (size_t)z * sliceE + i4);
    s.x += p.x; s.y += p.y; s.z += p.z; s.w += p.w;
  }
  const int c0 = i4 % ldc;
  float r[4] = {s.x, s.y, s.z, s.w};
  if (MODE == 1) {
    half4v o;
#pragma unroll
    for (int j = 0; j < 4; j++) {
      const int c = c0 + j;
      const float x = r[j] + bias[c];
      const float sc = g[c] / sqrtf(v[c] + 1e-3f);
      o[j] = (f16)fmaxf((x - m[c]) * sc + b[c], 0.f);
    }
    *(half4v*)((f16*)out + i4) = o;
  } else {
    float4 o;
    o.x = r[0] + bias[c0];
    o.y = r[1] + bias[c0 + 1];
    o.z = r[2] + bias[c0 + 2];
    o.w = r[3] + bias[c0 + 3];
    *(float4*)((float*)out + i4) = o;
  }
}

// ---- logits copy + softmax + bbox scatter ----
__global__ __launch_bounds__(128) void out_k(const float* __restrict__ lraw,
                                             float* __restrict__ out) {
  const int r = blockIdx.x, t = threadIdx.x;
  __shared__ float red[128];
  const float* row = lraw + (size_t)r * 512;
  const float lg = (t < 81) ? row[t] : -INFINITY;
  if (t < 81) out[(size_t)r * 81 + t] = lg;
  red[t] = lg;
  __syncthreads();
  for (int s = 64; s > 0; s >>= 1) {
    if (t < s) red[t] = fmaxf(red[t], red[t + s]);
    __syncthreads();
  }
  const float mx = red[0];
  __syncthreads();
  const float e = (t < 81) ? expf(lg - mx) : 0.f;
  red[t] = e;
  __syncthreads();
  for (int s = 64; s > 0; s >>= 1) {
    if (t < s) red[t] += red[t + s];
    __syncthreads();
  }
  const float inv = 1.f / red[0];
  if (t < 81) out[81000 + (size_t)r * 81 + t] = e * inv;
  for (int j = t; j < 324; j += 128) out[162000 + (size_t)r * 324 + j] = row[81 + j];
}

extern "C" void kernel_launch(void* const* d_in, const int* in_sizes, int n_in,
                              void* d_out, int out_size, void* d_ws, size_t ws_size,
                              hipStream_t stream) {
  const float* p2 = (const float*)d_in[0];
  const float* p3 = (const float*)d_in[1];
  const float* p4 = (const float*)d_in[2];
  const float* p5 = (const float*)d_in[3];
  const float* rois = (const float*)d_in[4];
  const float* conv1_w = (const float*)d_in[5];
  const float* conv1_b = (const float*)d_in[6];
  const float* bn1_g = (const float*)d_in[7];
  const float* bn1_b = (const float*)d_in[8];
  const float* bn1_m = (const float*)d_in[9];
  const float* bn1_v = (const float*)d_in[10];
  const float* conv2_w = (const float*)d_in[11];
  const float* conv2_b = (const float*)d_in[12];
  const float* bn2_g = (const float*)d_in[13];
  const float* bn2_b = (const float*)d_in[14];
  const float* bn2_m = (const float*)d_in[15];
  const float* bn2_v = (const float*)d_in[16];
  const float* logits_w = (const float*)d_in[17];
  const float* logits_b = (const float*)d_in[18];
  const float* bbox_w = (const float*)d_in[19];
  const float* bbox_b = (const float*)d_in[20];

  char* ws = (char*)d_ws;
  f16* fmapT = (f16*)ws;
  f16* sh1 = (f16*)(ws + (size_t)0);
  f16* sh2 = (f16*)(ws + ((size_t)2 << 20));
  float* lraw = (float*)(ws + ((size_t)4 << 20));
  f16* w2t = (f16*)(ws + ((size_t)6 << 20));
  f16* wcat = (f16*)(ws + ((size_t)8 << 20));
  float* bcat = (float*)(ws + ((size_t)9 << 20));
  float* part = (float*)(ws + ((size_t)10 << 20));
  f16* pooled = (f16*)(ws + (size_t)44564480);
  f16* w1t = (f16*)(ws + (size_t)70254592);

  // 1) fmap transpose to [pix][256] fp16 (all levels, one launch, 128px tiles)
  fmap_all_k<<<680, 256, 0, stream>>>(p2, p3, p4, p5, fmapT);
  // 2) w1 -> fp16 [k][pq*256+c]
  w1_t_k<<<1024, 256, 0, stream>>>(conv1_w, w1t);
  // 3) roi align (consumes fmapT)
  roi_align_k<<<512, 256, 0, stream>>>(rois, fmapT, pooled);
  // 4) small converts (alias fmapT region -> safe after roi, stream-sequential)
  prep_small_k<<<1537, 256, 0, stream>>>(conv2_w, logits_w, logits_b, bbox_w, bbox_b,
                                         w2t, wcat, bcat);
  // 5) GEMM1: [1024x12544] x [1024x12544]^T, split-K=8, deep-pipeline engine
  gemm1_d2<<<dim3(8, 4, 8), 512, 0, stream>>>(pooled, w1t, part, 12544, 1568);
  reduce_ep_k<8, 1><<<1024, 256, 0, stream>>>(part, 1048576, 1024, conv1_b, bn1_g,
                                              bn1_b, bn1_m, bn1_v, sh1);
  // 6) GEMM2: [1024x1024] x [1024x1024]^T, split-K=4
  gemm_nt_p3<<<dim3(8, 8, 4), 256, 0, stream>>>(sh1, w2t, part, 1024, 256, 1024);
  reduce_ep_k<4, 1><<<1024, 256, 0, stream>>>(part, 1048576, 1024, conv2_b, bn2_g,
                                              bn2_b, bn2_m, bn2_v, sh2);
  // 7) GEMM3: [1024x1024] x [512x1024]^T, split-K=8
  gemm_nt_p3<<<dim3(4, 8, 8), 256, 0, stream>>>(sh2, wcat, part, 1024, 128, 512);
  reduce_ep_k<8, 2><<<512, 256, 0, stream>>>(part, 524288, 512, bcat, nullptr,
                                             nullptr, nullptr, nullptr, lraw);
  // 8) outputs
  out_k<<<1000, 128, 0, stream>>>(lraw, (float*)d_out);
}

// Round 8
// 123.987 us; speedup vs baseline: 1.0365x; 1.0365x over previous
//
#include <hip/hip_runtime.h>
#include <hip/hip_fp16.h>
#include <math.h>

typedef _Float16 f16;
typedef _Float16 half8 __attribute__((ext_vector_type(8)));
typedef _Float16 half4v __attribute__((ext_vector_type(4)));
typedef _Float16 half2v __attribute__((ext_vector_type(2)));
typedef float f32x4 __attribute__((ext_vector_type(4)));

// ---------------- ws layout (bytes) ----------------
// region A [0, 44,564,480): fmapT fp16 [87040][256]   (levels: 0,65536,81920,86016 px)
//   aliased AFTER roi_align has consumed fmapT (stream-sequential):
//     sh1  @ 0MB  fp16 [1024][1024]
//     sh2  @ 2MB  fp16 [1024][1024]
//     w2t  @ 6MB  fp16 [1024][1024]
//     wcat @ 8MB  fp16 [512][1024]
//     bcat @ 9MB  fp32 [512]
//     part @10MB  fp32 [8][1024][1024] max = 32MB (ends 42MB < 44.56MB)
// pooled @ 44,564,480  fp16 [1024][49*256]
// w1t    @ 70,254,592  fp16 [1024][49*256]    (total 95,944,704 B)

__device__ __forceinline__ void gload16(const f16* g, f16* lds) {
  __builtin_amdgcn_global_load_lds(
      (const __attribute__((address_space(1))) unsigned int*)g,
      (__attribute__((address_space(3))) unsigned int*)lds, 16, 0, 0);
}

// ======== merged prep: fmap transpose (r7 body) + w1 repack (r3 body) ========
// Block roles interleaved 2:3 (fmap:w1t) so both run concurrently chip-wide.
__device__ __forceinline__ void fmap_body(int b, f16* tile,
                                          const float* __restrict__ p2,
                                          const float* __restrict__ p3,
                                          const float* __restrict__ p4,
                                          const float* __restrict__ p5,
                                          f16* __restrict__ dst0) {
  const float* src;
  int Ppix, p0;
  size_t dstoff;
  if (b < 512)      { src = p2; Ppix = 65536; dstoff = 0;     p0 = b * 128; }
  else if (b < 640) { src = p3; Ppix = 16384; dstoff = 65536; p0 = (b - 512) * 128; }
  else if (b < 672) { src = p4; Ppix = 4096;  dstoff = 81920; p0 = (b - 640) * 128; }
  else              { src = p5; Ppix = 1024;  dstoff = 86016; p0 = (b - 672) * 128; }
  const int t = threadIdx.x;
  const int px4 = (t & 31) * 4;
  const int cp = (t >> 5) * 2;
#pragma unroll 4
  for (int i = 0; i < 16; i++) {
    const int c = i * 16 + cp;
    const float4 va = *(const float4*)&src[(size_t)c * Ppix + p0 + px4];
    const float4 vb = *(const float4*)&src[(size_t)(c + 1) * Ppix + p0 + px4];
    const float a_[4] = {va.x, va.y, va.z, va.w};
    const float b_[4] = {vb.x, vb.y, vb.z, vb.w};
#pragma unroll
    for (int j = 0; j < 4; j++) {
      const int px = px4 + j;
      const int cs = c ^ (((px >> 2) & 31) << 3);
      half2v h = {(f16)a_[j], (f16)b_[j]};
      *(half2v*)&tile[px * 256 + cs] = h;
    }
  }
  __syncthreads();
  f16* d = dst0 + (dstoff + (size_t)p0) * 256;
  const int c8 = (t & 31) * 8;
#pragma unroll 4
  for (int i = 0; i < 16; i++) {
    const int px = (t >> 5) * 16 + i;
    const int c8s = c8 ^ (((px >> 2) & 31) << 3);
    const half8 o = *(const half8*)&tile[px * 256 + c8s];
    *(half8*)&d[px * 256 + c8] = o;
  }
}

__device__ __forceinline__ void w1t_body(int k, f16* tile,
                                         const float* __restrict__ w1,
                                         f16* __restrict__ w1t) {
  const int t = threadIdx.x;
  const float* src = w1 + (size_t)k * 12544;
  f16* dst = w1t + (size_t)k * 12544;
#pragma unroll 7
  for (int i = 0; i < 49; i++) {
    const int idx = i * 256 + t;  // = c*49 + pq
    const int c = idx / 49, pq = idx % 49;
    tile[pq * 260 + c] = (f16)src[idx];
  }
  __syncthreads();
#pragma unroll
  for (int i = 0; i < 7; i++) {
    const int h8 = i * 256 + t;
    if (h8 < 1568) {
      const int pq = h8 >> 5, c8 = (h8 & 31) * 8;
      const half4v lo = *(const half4v*)&tile[pq * 260 + c8];
      const half4v hi = *(const half4v*)&tile[pq * 260 + c8 + 4];
      half8 o;
      o[0] = lo[0]; o[1] = lo[1]; o[2] = lo[2]; o[3] = lo[3];
      o[4] = hi[0]; o[5] = hi[1]; o[6] = hi[2]; o[7] = hi[3];
      *(half8*)&dst[pq * 256 + c8] = o;
    }
  }
}

// grid = 1710: group of 5 = {2 fmap, 3 w1t}; fmap ids 0..679, w1t ids 0..1023.
__global__ __launch_bounds__(256) void prep_big_k(const float* __restrict__ p2,
                                                  const float* __restrict__ p3,
                                                  const float* __restrict__ p4,
                                                  const float* __restrict__ p5,
                                                  const float* __restrict__ conv1_w,
                                                  f16* __restrict__ fmapT,
                                                  f16* __restrict__ w1t) {
  __shared__ __align__(16) f16 buf[32768];  // 64 KB union
  const int bid = blockIdx.x;
  const int g = bid / 5, r = bid % 5;
  if (r < 2) {
    const int fb = g * 2 + r;
    if (fb < 680) fmap_body(fb, buf, p2, p3, p4, p5, fmapT);
  } else {
    const int wb = g * 3 + (r - 2);
    if (wb < 1024) w1t_body(wb, buf, conv1_w, w1t);
  }
}

// ---- merged small converts (r3-proven) ----
__global__ void prep_small_k(const float* __restrict__ conv2_w,
                             const float* __restrict__ lw, const float* __restrict__ lb,
                             const float* __restrict__ bw, const float* __restrict__ bb,
                             f16* __restrict__ w2t, f16* __restrict__ wcat,
                             float* __restrict__ bcat) {
  const int i = blockIdx.x * 256 + threadIdx.x;
  if (i < 262144) {
    const float4 v = ((const float4*)conv2_w)[i];
    half4v o = {(f16)v.x, (f16)v.y, (f16)v.z, (f16)v.w};
    ((half4v*)w2t)[i] = o;
  } else if (i < 262144 + 131072) {
    const int idx4 = i - 262144;
    const int elem = idx4 * 4;
    const int row = elem >> 10, col = elem & 1023;
    half4v o;
#pragma unroll
    for (int j = 0; j < 4; j++) {
      float v = 0.f;
      if (row < 81) v = lw[row * 1024 + col + j];
      else if (row < 405) v = bw[(row - 81) * 1024 + col + j];
      o[j] = (f16)v;
    }
    ((half4v*)wcat)[idx4] = o;
  } else if (i < 262144 + 131072 + 128) {
    const int j = (i - 393216) * 4;
    float r[4];
#pragma unroll
    for (int q = 0; q < 4; q++) {
      const int c = j + q;
      float bv = 0.f;
      if (c < 81) bv = lb[c];
      else if (c < 405) bv = bb[c - 81];
      r[q] = bv;
    }
    float4 o;
    o.x = r[0]; o.y = r[1]; o.z = r[2]; o.w = r[3];
    *(float4*)&bcat[j] = o;
  }
}

// ---- roi align (r3-proven): 2 rois/block, half2 loads; rows>=1000 zeroed ----
__global__ __launch_bounds__(256) void roi_align_k(const float* __restrict__ rois,
                                                   const f16* __restrict__ fmapT,
                                                   f16* __restrict__ pooled) {
  const int t = threadIdx.x;
  const int hf = t >> 7, tp = t & 127;
  const int r = blockIdx.x * 2 + hf;
  __shared__ int s_lo[2][14], s_hi[2][14], s_val[2][14];
  __shared__ float s_w[2][14];
  const bool live = (r < 1000);
  int H = 2, off = 0;
  if (live) {
    const float x1 = rois[r * 4 + 0], y1 = rois[r * 4 + 1];
    const float x2 = rois[r * 4 + 2], y2 = rois[r * 4 + 3];
    const float s = sqrtf(fmaxf((y2 - y1) * (x2 - x1), 0.f));
    const float lf = logf(s / 224.0f) / 0.69314718055994531f;
    int lv = (int)rintf(lf) + 4;
    lv = lv < 2 ? 2 : (lv > 5 ? 5 : lv);
    const int li = lv - 2;
    H = 256 >> li;
    off = (li == 0) ? 0 : (li == 1) ? 65536 : (li == 2) ? 81920 : 86016;
    const float Hm1 = (float)(H - 1);
    if (tp < 14) {
      const bool isx = tp >= 7;
      const int i = isx ? tp - 7 : tp;
      const float b1 = (isx ? x1 : y1) * (1.0f / 1024.0f);
      const float b2 = (isx ? x2 : y2) * (1.0f / 1024.0f);
      const float g = (float)i / 6.0f;
      const float coord = b1 * Hm1 + g * ((b2 - b1) * Hm1);
      const int valid = (coord >= 0.f) && (coord <= Hm1);
      float c = fminf(fmaxf(coord, 0.f), Hm1);
      float lo = floorf(c);
      s_lo[hf][tp] = (int)lo;
      s_hi[hf][tp] = (int)fminf(lo + 1.f, Hm1);
      s_w[hf][tp] = c - lo;
      s_val[hf][tp] = valid;
    }
  }
  __syncthreads();
  f16* outp = pooled + (size_t)r * 12544 + 2 * tp;
  if (!live) {
#pragma unroll 7
    for (int i = 0; i < 49; i++) {
      half2v z = {(f16)0.f, (f16)0.f};
      *(half2v*)&outp[i * 256] = z;
    }
    return;
  }
  const f16* base = fmapT + (size_t)off * 256 + 2 * tp;
  for (int py = 0; py < 7; py++) {
    const int ylo = s_lo[hf][py], yhi = s_hi[hf][py], vy = s_val[hf][py];
    const float wy = s_w[hf][py];
    for (int px = 0; px < 7; px++) {
      const int xlo = s_lo[hf][7 + px], xhi = s_hi[hf][7 + px], vx = s_val[hf][7 + px];
      const float wx = s_w[hf][7 + px];
      const half2v v00 = *(const half2v*)&base[(size_t)(ylo * H + xlo) * 256];
      const half2v v01 = *(const half2v*)&base[(size_t)(ylo * H + xhi) * 256];
      const half2v v10 = *(const half2v*)&base[(size_t)(yhi * H + xlo) * 256];
      const half2v v11 = *(const half2v*)&base[(size_t)(yhi * H + xhi) * 256];
      half2v o;
#pragma unroll
      for (int q = 0; q < 2; q++) {
        const float top = (float)v00[q] * (1.f - wx) + (float)v01[q] * wx;
        const float bot = (float)v10[q] * (1.f - wx) + (float)v11[q] * wx;
        float vv = top * (1.f - wy) + bot * wy;
        if (!(vy && vx)) vv = 0.f;
        o[q] = (f16)vv;
      }
      *(half2v*)&outp[(py * 7 + px) * 256] = o;
    }
  }
}

// ---- GEMM1 engine v2 (r5-proven): 8-wave 256x128, BK=32, 4-slot ring ----
__global__ __launch_bounds__(512) void gemm1_d2(
    const f16* __restrict__ A, const f16* __restrict__ B, float* __restrict__ part,
    int K, int kPerSplit) {
  __shared__ __align__(16) f16 As[4][256 * 32];   // 64 KB
  __shared__ __align__(16) f16 Bs[4][128 * 32];   // 32 KB
  const int t = threadIdx.x;

  int lid = blockIdx.x + 8 * (blockIdx.y + 4 * blockIdx.z);
  const int chunk = (8 * 4 * (int)gridDim.z) >> 3;
  lid = (lid & 7) * chunk + (lid >> 3);
  const int bx = lid & 7;
  const int by = (lid >> 3) & 3;
  const int bz = lid >> 5;

  const int m0 = by * 256, n0 = bx * 128;
  const int wid = t >> 6, lane = t & 63;
  const int wr = (wid & 3) * 64;   // 4 M-waves
  const int wc = (wid >> 2) * 64;  // 2 N-waves
  const int lrow = lane & 15;
  const int lsl = lane >> 4;
  const int srow = t >> 2;                              // 0..127 staging row
  const int scol = (((t & 3) ^ ((t >> 3) & 3)) << 3);   // pre-swizzled source slot
  const int kz0 = bz * kPerSplit;
  const int nIter = kPerSplit >> 5;

  f32x4 acc[4][4] = {};
  const f16* Ab = A + (size_t)(m0 + srow) * K + kz0 + scol;
  const f16* Bb = B + (size_t)(n0 + srow) * K + kz0 + scol;
  f16* asb = &As[0][0] + wid * 512;  // wave-uniform base within slot
  f16* bsb = &Bs[0][0] + wid * 512;

  // one stage group per K-tile: 3 gload_lds, emission order pinned
#define STG(kt) do {                                                           \
    const int sl_ = (kt) & 3; const size_t ko_ = (size_t)(kt) * 32;            \
    gload16(Ab + ko_, asb + sl_ * 8192);                                       \
    gload16(Ab + (size_t)128 * K + ko_, asb + sl_ * 8192 + 4096);              \
    gload16(Bb + ko_, bsb + sl_ * 4096);                                       \
    __builtin_amdgcn_sched_barrier(0);                                         \
  } while (0)

  STG(0);
  STG(1);
  asm volatile("s_waitcnt vmcnt(3)" ::: "memory");  // tile 0 resident
  __builtin_amdgcn_sched_barrier(0);
  __builtin_amdgcn_s_barrier();

  for (int kt = 0; kt < nIter; ++kt) {
    const int sl = kt & 3;
    const f16* as = &As[sl][0];
    const f16* bs = &Bs[sl][0];
    half8 aF[4], bF[4];
#pragma unroll
    for (int m = 0; m < 4; m++) {
      const int r_ = wr + m * 16 + lrow;
      aF[m] = *(const half8*)&as[r_ * 32 + ((lsl ^ ((r_ >> 1) & 3)) << 3)];
    }
#pragma unroll
    for (int n = 0; n < 4; n++) {
      const int r_ = wc + n * 16 + lrow;
      bF[n] = *(const half8*)&bs[r_ * 32 + ((lsl ^ ((r_ >> 1) & 3)) << 3)];
    }
    if (kt + 2 < nIter) STG(kt + 2);
    __builtin_amdgcn_s_setprio(1);
#pragma unroll
    for (int m = 0; m < 4; m++)
#pragma unroll
      for (int n = 0; n < 4; n++)
        acc[m][n] = __builtin_amdgcn_mfma_f32_16x16x32_f16(aF[m], bF[n], acc[m][n], 0, 0, 0);
    __builtin_amdgcn_s_setprio(0);
    // drain tile kt+1's 3 loads (kt+2's stay in flight); all waves sync
    if (kt + 2 < nIter) { asm volatile("s_waitcnt vmcnt(3)" ::: "memory"); }
    else                { asm volatile("s_waitcnt vmcnt(0)" ::: "memory"); }
    __builtin_amdgcn_sched_barrier(0);
    __builtin_amdgcn_s_barrier();
  }
#undef STG

  float* outp = part + (size_t)bz * (1024 * 1024);
#pragma unroll
  for (int m = 0; m < 4; m++) {
    const int rr = m0 + wr + m * 16 + lsl * 4;
#pragma unroll
    for (int n = 0; n < 4; n++) {
      const int cc = n0 + wc + n * 16 + lrow;
#pragma unroll
      for (int j = 0; j < 4; j++)
        outp[(size_t)(rr + j) * 1024 + cc] = acc[m][n][j];
    }
  }
}

// ---- GEMM2/3 engine (r3-proven): 3-buffer pipeline, fp32 partials ----
__global__ __launch_bounds__(256) void gemm_nt_p3(
    const f16* __restrict__ A, const f16* __restrict__ B, float* __restrict__ part,
    int K, int kPerSplit, int ldc) {
  __shared__ __align__(16) f16 As[3][128 * 32];
  __shared__ __align__(16) f16 Bs[3][128 * 32];
  const int t = threadIdx.x;

  const int gx = gridDim.x, gy = gridDim.y;
  int lid = blockIdx.x + gx * (blockIdx.y + gy * blockIdx.z);
  const int chunk = (gx * gy * (int)gridDim.z) >> 3;
  lid = (lid & 7) * chunk + (lid >> 3);
  const int bx = lid % gx;
  const int tmp = lid / gx;
  const int by = tmp % gy;
  const int bz = tmp / gy;

  const int m0 = by * 128;
  const int n0 = bx * 128;
  const int wid = t >> 6;
  const int lane = t & 63;
  const int wr = (wid >> 1) * 64;
  const int wc = (wid & 1) * 64;
  const int lrow = lane & 15;
  const int lsl = lane >> 4;
  const int rowA = t >> 2;
  const int c8 = (((t & 3) ^ ((rowA >> 1) & 3)) << 3);
  const int kz0 = bz * kPerSplit;
  const int nIter = kPerSplit >> 5;

  f32x4 acc[4][4] = {};
  const f16* Ab = A + (size_t)m0 * K + kz0 + c8;
  const f16* Bb = B + (size_t)n0 * K + kz0 + c8;

#define STAGE(buf, it)                                                        \
  do {                                                                        \
    const int ko = (it) * 32;                                                 \
    gload16(Ab + (size_t)rowA * K + ko, &As[buf][wid * 512]);                 \
    gload16(Ab + (size_t)(rowA + 64) * K + ko, &As[buf][2048 + wid * 512]);   \
    gload16(Bb + (size_t)rowA * K + ko, &Bs[buf][wid * 512]);                 \
    gload16(Bb + (size_t)(rowA + 64) * K + ko, &Bs[buf][2048 + wid * 512]);   \
  } while (0)

#define COMPUTE(buf)                                                          \
  do {                                                                        \
    half8 aF[4], bF[4];                                                       \
    _Pragma("unroll") for (int m = 0; m < 4; m++) {                           \
      const int rr_ = wr + m * 16 + lrow;                                     \
      aF[m] = *(const half8*)&As[buf][rr_ * 32 + ((lsl ^ ((rr_ >> 1) & 3)) << 3)]; \
    }                                                                         \
    _Pragma("unroll") for (int n = 0; n < 4; n++) {                           \
      const int rr_ = wc + n * 16 + lrow;                                     \
      bF[n] = *(const half8*)&Bs[buf][rr_ * 32 + ((lsl ^ ((rr_ >> 1) & 3)) << 3)]; \
    }                                                                         \
    __builtin_amdgcn_s_setprio(1);                                            \
    _Pragma("unroll") for (int m = 0; m < 4; m++)                             \
      _Pragma("unroll") for (int n = 0; n < 4; n++)                           \
        acc[m][n] = __builtin_amdgcn_mfma_f32_16x16x32_f16(aF[m], bF[n], acc[m][n], 0, 0, 0); \
    __builtin_amdgcn_s_setprio(0);                                            \
  } while (0)

  STAGE(0, 0);
  STAGE(1, 1);
  int bc = 0;
  for (int it = 0; it < nIter - 2; ++it) {
    const int bs_ = (bc == 0) ? 2 : bc - 1;
    STAGE(bs_, it + 2);
    asm volatile("s_waitcnt vmcnt(8)" ::: "memory");
    __builtin_amdgcn_sched_barrier(0);
    __builtin_amdgcn_s_barrier();
    COMPUTE(bc);
    __builtin_amdgcn_s_barrier();
    bc = (bc == 2) ? 0 : bc + 1;
  }
  asm volatile("s_waitcnt vmcnt(4)" ::: "memory");
  __builtin_amdgcn_sched_barrier(0);
  __builtin_amdgcn_s_barrier();
  COMPUTE(bc);
  __builtin_amdgcn_s_barrier();
  bc = (bc == 2) ? 0 : bc + 1;
  asm volatile("s_waitcnt vmcnt(0)" ::: "memory");
  __builtin_amdgcn_sched_barrier(0);
  __builtin_amdgcn_s_barrier();
  COMPUTE(bc);
#undef STAGE
#undef COMPUTE

  const size_t slice = (size_t)gy * 128 * ldc;
#pragma unroll
  for (int m = 0; m < 4; m++) {
#pragma unroll
    for (int n = 0; n < 4; n++) {
#pragma unroll
      for (int j = 0; j < 4; j++) {
        const int rr = m0 + wr + m * 16 + ((lane >> 4) << 2) + j;
        const int cc = n0 + wc + n * 16 + (lane & 15);
        part[(size_t)bz * slice + (size_t)rr * ldc + cc] = acc[m][n][j];
      }
    }
  }
}

// ---- split-K reduce + epilogue (MODE 1 only now): bias+BN+ReLU->f16 ----
template <int Z>
__global__ void reduce_ep_k(const float* __restrict__ part, int sliceE, int ldc,
                            const float* __restrict__ bias, const float* __restrict__ g,
                            const float* __restrict__ b, const float* __restrict__ m,
                            const float* __restrict__ v, f16* __restrict__ out) {
  const int i4 = (blockIdx.x * 256 + threadIdx.x) * 4;
  float4 s = *(const float4*)(part + i4);
#pragma unroll
  for (int z = 1; z < Z; z++) {
    const float4 p = *(const float4*)(part + (size_t)z * sliceE + i4);
    s.x += p.x; s.y += p.y; s.z += p.z; s.w += p.w;
  }
  const int c0 = i4 % ldc;
  float r[4] = {s.x, s.y, s.z, s.w};
  half4v o;
#pragma unroll
  for (int j = 0; j < 4; j++) {
    const int c = c0 + j;
    const float x = r[j] + bias[c];
    const float sc = g[c] / sqrtf(v[c] + 1e-3f);
    o[j] = (f16)fmaxf((x - m[c]) * sc + b[c], 0.f);
  }
  *(half4v*)(out + i4) = o;
}

// ---- fused: reduce GEMM3 partials (8 slices) + bias + softmax + scatter ----
// part layout from gemm3: [z][1024][512], slice = 524288 floats. block = roi row.
__global__ __launch_bounds__(256) void reduce3_out_k(const float* __restrict__ part,
                                                     const float* __restrict__ bcat,
                                                     float* __restrict__ out) {
  const int r = blockIdx.x, t = threadIdx.x;
  __shared__ float red[256];
  const float* base = part + (size_t)r * 512;
  float v0 = 0.f, v1 = 0.f;
  {
    float s = bcat[t];
#pragma unroll
    for (int z = 0; z < 8; z++) s += base[(size_t)z * 524288 + t];
    v0 = s;
  }
  if (t < 149) {
    float s = bcat[256 + t];
#pragma unroll
    for (int z = 0; z < 8; z++) s += base[(size_t)z * 524288 + 256 + t];
    v1 = s;
  }
  // softmax over cols 0..80 (in v0 for t<81)
  red[t] = (t < 81) ? v0 : -INFINITY;
  __syncthreads();
  for (int s_ = 128; s_ > 0; s_ >>= 1) {
    if (t < s_) red[t] = fmaxf(red[t], red[t + s_]);
    __syncthreads();
  }
  const float mx = red[0];
  __syncthreads();
  const float e = (t < 81) ? expf(v0 - mx) : 0.f;
  red[t] = e;
  __syncthreads();
  for (int s_ = 128; s_ > 0; s_ >>= 1) {
    if (t < s_) red[t] += red[t + s_];
    __syncthreads();
  }
  const float inv = 1.f / red[0];
  if (t < 81) {
    out[(size_t)r * 81 + t] = v0;
    out[81000 + (size_t)r * 81 + t] = e * inv;
  }
  // bbox cols 81..404 -> out[162000 + r*324 + (c-81)]
  if (t >= 81) out[162000 + (size_t)r * 324 + (t - 81)] = v0;
  if (t < 149) out[162000 + (size_t)r * 324 + 175 + t] = v1;
}

extern "C" void kernel_launch(void* const* d_in, const int* in_sizes, int n_in,
                              void* d_out, int out_size, void* d_ws, size_t ws_size,
                              hipStream_t stream) {
  const float* p2 = (const float*)d_in[0];
  const float* p3 = (const float*)d_in[1];
  const float* p4 = (const float*)d_in[2];
  const float* p5 = (const float*)d_in[3];
  const float* rois = (const float*)d_in[4];
  const float* conv1_w = (const float*)d_in[5];
  const float* conv1_b = (const float*)d_in[6];
  const float* bn1_g = (const float*)d_in[7];
  const float* bn1_b = (const float*)d_in[8];
  const float* bn1_m = (const float*)d_in[9];
  const float* bn1_v = (const float*)d_in[10];
  const float* conv2_w = (const float*)d_in[11];
  const float* conv2_b = (const float*)d_in[12];
  const float* bn2_g = (const float*)d_in[13];
  const float* bn2_b = (const float*)d_in[14];
  const float* bn2_m = (const float*)d_in[15];
  const float* bn2_v = (const float*)d_in[16];
  const float* logits_w = (const float*)d_in[17];
  const float* logits_b = (const float*)d_in[18];
  const float* bbox_w = (const float*)d_in[19];
  const float* bbox_b = (const float*)d_in[20];

  char* ws = (char*)d_ws;
  f16* fmapT = (f16*)ws;
  f16* sh1 = (f16*)(ws + (size_t)0);
  f16* sh2 = (f16*)(ws + ((size_t)2 << 20));
  f16* w2t = (f16*)(ws + ((size_t)6 << 20));
  f16* wcat = (f16*)(ws + ((size_t)8 << 20));
  float* bcat = (float*)(ws + ((size_t)9 << 20));
  float* part = (float*)(ws + ((size_t)10 << 20));
  f16* pooled = (f16*)(ws + (size_t)44564480);
  f16* w1t = (f16*)(ws + (size_t)70254592);

  // 1) fmap transpose + w1 repack, merged & interleaved (independent outputs)
  prep_big_k<<<1710, 256, 0, stream>>>(p2, p3, p4, p5, conv1_w, fmapT, w1t);
  // 2) roi align (consumes fmapT)
  roi_align_k<<<512, 256, 0, stream>>>(rois, fmapT, pooled);
  // 3) small converts (alias fmapT region -> safe after roi, stream-sequential)
  prep_small_k<<<1537, 256, 0, stream>>>(conv2_w, logits_w, logits_b, bbox_w, bbox_b,
                                         w2t, wcat, bcat);
  // 4) GEMM1: split-K=8, deep-pipeline engine
  gemm1_d2<<<dim3(8, 4, 8), 512, 0, stream>>>(pooled, w1t, part, 12544, 1568);
  reduce_ep_k<8><<<1024, 256, 0, stream>>>(part, 1048576, 1024, conv1_b, bn1_g,
                                           bn1_b, bn1_m, bn1_v, sh1);
  // 5) GEMM2: split-K=4
  gemm_nt_p3<<<dim3(8, 8, 4), 256, 0, stream>>>(sh1, w2t, part, 1024, 256, 1024);
  reduce_ep_k<4><<<1024, 256, 0, stream>>>(part, 1048576, 1024, conv2_b, bn2_g,
                                           bn2_b, bn2_m, bn2_v, sh2);
  // 6) GEMM3: split-K=8
  gemm_nt_p3<<<dim3(4, 8, 8), 256, 0, stream>>>(sh2, wcat, part, 1024, 128, 512);
  // 7) fused reduce3 + softmax + output scatter
  reduce3_out_k<<<1000, 256, 0, stream>>>(part, bcat, (float*)d_out);
}